// Round 1
// baseline (191.675 us; speedup 1.0000x reference)
//
#include <hip/hip_runtime.h>
#include <math.h>

// Softmax aggregation (scatter_softmax + weighted segment_sum), single pass.
// x: [N, 4, 64] fp32, idx: [N] int32 SORTED ascending in [0,S),
// out: [4, S, 64] fp32.
// One wave (64 lanes) per segment; lane l owns elements [4l, 4l+4) of the
// 256-wide row => float4 loads, fully coalesced (1KB per wave per row).
// Online softmax: running max m, rescaled sum & weighted accumulator.

#define WPB 4  // waves per block (256 threads)

__global__ __launch_bounds__(256) void softmax_agg_kernel(
    const float* __restrict__ x,
    const float* __restrict__ beta_p,
    const int* __restrict__ idx,
    float* __restrict__ out,
    int N, int S)
{
    const int wave = threadIdx.x >> 6;
    const int lane = threadIdx.x & 63;
    const int s = blockIdx.x * WPB + wave;
    if (s >= S) return;

    // Two interleaved binary searches over sorted idx:
    // start = lower_bound(idx, s), end = lower_bound(idx, s+1)
    int lo0 = 0, hi0 = N;
    int lo1 = 0, hi1 = N;
    while (lo0 < hi0 || lo1 < hi1) {
        if (lo0 < hi0) {
            int mid = (lo0 + hi0) >> 1;
            if (idx[mid] < s) lo0 = mid + 1; else hi0 = mid;
        }
        if (lo1 < hi1) {
            int mid = (lo1 + hi1) >> 1;
            if (idx[mid] < s + 1) lo1 = mid + 1; else hi1 = mid;
        }
    }
    const int start = lo0;
    const int end   = lo1;

    // Output element (c, s, d) at c*S*64 + s*64 + d.
    // Lane l covers t = 4l..4l+3 => c = l>>4, d = (l&15)*4 .. +3 (float4-aligned).
    const int c = lane >> 4;
    const long out_f4 = ((long)c * S + s) * 16 + (lane & 15);
    float4* __restrict__ out4 = reinterpret_cast<float4*>(out);

    if (start >= end) {  // empty segment -> zeros (reference: segment_sum identity)
        out4[out_f4] = make_float4(0.f, 0.f, 0.f, 0.f);
        return;
    }

    const float beta = *beta_p;
    const float4* __restrict__ x4 = reinterpret_cast<const float4*>(x);

    float m0 = -INFINITY, m1 = -INFINITY, m2 = -INFINITY, m3 = -INFINITY;
    float s0 = 0.f, s1 = 0.f, s2 = 0.f, s3 = 0.f;
    float a0 = 0.f, a1 = 0.f, a2 = 0.f, a3 = 0.f;

    for (int n = start; n < end; ++n) {
        float4 v = x4[(long)n * 64 + lane];

        {
            float z  = beta * v.x;
            float mn = fmaxf(m0, z);
            float cr = __expf(m0 - mn);   // rescale factor (exp(-inf)=0 on first iter)
            float e  = __expf(z - mn);
            s0 = s0 * cr + e;
            a0 = a0 * cr + e * v.x;
            m0 = mn;
        }
        {
            float z  = beta * v.y;
            float mn = fmaxf(m1, z);
            float cr = __expf(m1 - mn);
            float e  = __expf(z - mn);
            s1 = s1 * cr + e;
            a1 = a1 * cr + e * v.y;
            m1 = mn;
        }
        {
            float z  = beta * v.z;
            float mn = fmaxf(m2, z);
            float cr = __expf(m2 - mn);
            float e  = __expf(z - mn);
            s2 = s2 * cr + e;
            a2 = a2 * cr + e * v.z;
            m2 = mn;
        }
        {
            float z  = beta * v.w;
            float mn = fmaxf(m3, z);
            float cr = __expf(m3 - mn);
            float e  = __expf(z - mn);
            s3 = s3 * cr + e;
            a3 = a3 * cr + e * v.w;
            m3 = mn;
        }
    }

    out4[out_f4] = make_float4(a0 / s0, a1 / s1, a2 / s2, a3 / s3);
}

extern "C" void kernel_launch(void* const* d_in, const int* in_sizes, int n_in,
                              void* d_out, int out_size, void* d_ws, size_t ws_size,
                              hipStream_t stream) {
    const float* x      = (const float*)d_in[0];
    const float* beta_p = (const float*)d_in[1];
    const int*   idx    = (const int*)d_in[2];
    // d_in[3] = dim (always 0), d_in[4] = dim_size (== S) -- derived on host below.
    float* out = (float*)d_out;

    const int N = in_sizes[2];          // number of rows / edges
    const int S = out_size / 256;       // out is [4, S, 64]

    const int blocks = (S + WPB - 1) / WPB;
    softmax_agg_kernel<<<blocks, 256, 0, stream>>>(x, beta_p, idx, out, N, S);
}

// Round 3
// 121.515 us; speedup vs baseline: 1.5774x; 1.5774x over previous
//
#include <hip/hip_runtime.h>
#include <math.h>

// Softmax aggregation (scatter_softmax + weighted segment_sum), single pass.
// x: [N, 4, 64] fp32, idx: [N] int32 SORTED ascending in [0,S),
// out: [4, S, 64] fp32.
//
// Kernel 1 (seg_bounds): start[s] = lower_bound(idx, s) for s in [0, S],
// written to d_ws. O(N), fully coalesced, removes the per-wave binary search.
//
// Kernel 2: one wave per segment; lane l owns elements [4l, 4l+4) of the
// 256-wide row => float4 loads, 1KB per wave per row, fully coalesced.
// Online softmax; inner loop software-pipelined 4 rows deep (load next
// batch while processing current) to hide HBM latency.

#define WPB 4  // waves per block (256 threads)

__global__ __launch_bounds__(256) void seg_bounds_kernel(
    const int* __restrict__ idx, int* __restrict__ start, int N, int S)
{
    int n = blockIdx.x * blockDim.x + threadIdx.x;
    if (n >= N) return;
    int cur = idx[n];
    if (n == 0) {
        for (int s = 0; s <= cur; ++s) start[s] = 0;
    } else {
        int prev = idx[n - 1];
        for (int s = prev + 1; s <= cur; ++s) start[s] = n;
    }
    if (n == N - 1) {
        for (int s = cur + 1; s <= S; ++s) start[s] = N;
    }
}

__global__ __launch_bounds__(256) void softmax_agg_kernel(
    const float* __restrict__ x,
    const float* __restrict__ beta_p,
    const int* __restrict__ idx,
    const int* __restrict__ seg_start,   // null => do binary search
    float* __restrict__ out,
    int N, int S)
{
    const int wave = threadIdx.x >> 6;
    const int lane = threadIdx.x & 63;
    const int s = blockIdx.x * WPB + wave;
    if (s >= S) return;

    int start, end;
    if (seg_start) {
        start = seg_start[s];
        end   = seg_start[s + 1];
    } else {
        int lo0 = 0, hi0 = N, lo1 = 0, hi1 = N;
        while (lo0 < hi0 || lo1 < hi1) {
            if (lo0 < hi0) {
                int mid = (lo0 + hi0) >> 1;
                if (idx[mid] < s) lo0 = mid + 1; else hi0 = mid;
            }
            if (lo1 < hi1) {
                int mid = (lo1 + hi1) >> 1;
                if (idx[mid] < s + 1) lo1 = mid + 1; else hi1 = mid;
            }
        }
        start = lo0; end = lo1;
    }

    // Output element (c, s, d) at c*S*64 + s*64 + d.
    // Lane l covers c = l>>4, d = (l&15)*4 .. +3 (float4-aligned).
    const int c = lane >> 4;
    const long out_f4 = ((long)c * S + s) * 16 + (lane & 15);
    float4* __restrict__ out4 = reinterpret_cast<float4*>(out);

    if (start >= end) {  // empty segment -> zeros (segment_sum identity)
        out4[out_f4] = make_float4(0.f, 0.f, 0.f, 0.f);
        return;
    }

    const float beta = *beta_p;
    const float4* __restrict__ x4 = reinterpret_cast<const float4*>(x);

    float ml[4] = {-INFINITY, -INFINITY, -INFINITY, -INFINITY};
    float sm[4] = {0.f, 0.f, 0.f, 0.f};
    float ac[4] = {0.f, 0.f, 0.f, 0.f};

#define PROC(v) {                                                   \
        float va[4] = {(v).x, (v).y, (v).z, (v).w};                 \
        _Pragma("unroll")                                           \
        for (int cc = 0; cc < 4; ++cc) {                            \
            float z  = beta * va[cc];                               \
            float mn = fmaxf(ml[cc], z);                            \
            float cr = __expf(ml[cc] - mn);                         \
            float e  = __expf(z - mn);                              \
            sm[cc] = sm[cc] * cr + e;                               \
            ac[cc] = ac[cc] * cr + e * va[cc];                      \
            ml[cc] = mn;                                            \
        }                                                           \
    }

    int n   = start;
    int cnt = end - start;

    if (cnt >= 4) {
        // software pipeline, 4 rows deep
        float4 a0 = x4[(long)(n + 0) * 64 + lane];
        float4 a1 = x4[(long)(n + 1) * 64 + lane];
        float4 a2 = x4[(long)(n + 2) * 64 + lane];
        float4 a3 = x4[(long)(n + 3) * 64 + lane];
        n += 4; cnt -= 4;
        while (cnt >= 4) {
            float4 b0 = x4[(long)(n + 0) * 64 + lane];
            float4 b1 = x4[(long)(n + 1) * 64 + lane];
            float4 b2 = x4[(long)(n + 2) * 64 + lane];
            float4 b3 = x4[(long)(n + 3) * 64 + lane];
            PROC(a0); PROC(a1); PROC(a2); PROC(a3);
            a0 = b0; a1 = b1; a2 = b2; a3 = b3;
            n += 4; cnt -= 4;
        }
        PROC(a0); PROC(a1); PROC(a2); PROC(a3);
    }
    while (cnt > 0) {
        float4 v = x4[(long)n * 64 + lane];
        PROC(v);
        ++n; --cnt;
    }
#undef PROC

    out4[out_f4] = make_float4(ac[0] / sm[0], ac[1] / sm[1],
                               ac[2] / sm[2], ac[3] / sm[3]);
}

extern "C" void kernel_launch(void* const* d_in, const int* in_sizes, int n_in,
                              void* d_out, int out_size, void* d_ws, size_t ws_size,
                              hipStream_t stream) {
    const float* x      = (const float*)d_in[0];
    const float* beta_p = (const float*)d_in[1];
    const int*   idx    = (const int*)d_in[2];
    float* out = (float*)d_out;

    const int N = in_sizes[2];          // number of rows / edges
    const int S = out_size / 256;       // out is [4, S, 64]

    int* seg_start = nullptr;
    if (ws_size >= (size_t)(S + 1) * sizeof(int)) {
        seg_start = (int*)d_ws;
        seg_bounds_kernel<<<(N + 255) / 256, 256, 0, stream>>>(idx, seg_start, N, S);
    }

    const int blocks = (S + WPB - 1) / WPB;
    softmax_agg_kernel<<<blocks, 256, 0, stream>>>(x, beta_p, idx, seg_start, out, N, S);
}

// Round 5
// 115.071 us; speedup vs baseline: 1.6657x; 1.0560x over previous
//
#include <hip/hip_runtime.h>
#include <math.h>

// Softmax aggregation (scatter_softmax + weighted segment_sum), single pass.
// x: [N, 4, 64] fp32, idx: [N] int32 SORTED ascending in [0,S),
// out: [4, S, 64] fp32.
//
// Kernel 1 (seg_bounds): start[s] = lower_bound(idx, s) for s in [0, S] -> d_ws.
//
// Kernel 2: one wave per segment; lane l owns elements [4l, 4l+4) of the
// 256-wide row => float4 loads, 1KB per wave per row, fully coalesced.
// Online softmax. Inner loop is an UNCONDITIONAL 4-deep software pipeline:
// every batch of 4 rows is prefetched while the previous batch is processed;
// out-of-range slots are clamped to the last row (cache-hit dup loads) and
// masked via z = -2e30 (=> e = 0, cr = 1, state unchanged). ml starts at
// -1e30 (not -inf) so masked slots never produce NaN; slot 0 of each batch
// is always valid so ml is real before any masked slot.

#define WPB 4  // waves per block (256 threads)

typedef float f32x4 __attribute__((ext_vector_type(4)));  // clang vector: OK for nontemporal builtins

__global__ __launch_bounds__(256) void seg_bounds_kernel(
    const int* __restrict__ idx, int* __restrict__ start, int N, int S)
{
    int n = blockIdx.x * blockDim.x + threadIdx.x;
    if (n >= N) return;
    int cur = idx[n];
    if (n == 0) {
        for (int s = 0; s <= cur; ++s) start[s] = 0;
    } else {
        int prev = idx[n - 1];
        for (int s = prev + 1; s <= cur; ++s) start[s] = n;
    }
    if (n == N - 1) {
        for (int s = cur + 1; s <= S; ++s) start[s] = N;
    }
}

__global__ __launch_bounds__(256) void softmax_agg_kernel(
    const float* __restrict__ x,
    const float* __restrict__ beta_p,
    const int* __restrict__ idx,
    const int* __restrict__ seg_start,   // null => do binary search
    float* __restrict__ out,
    int N, int S)
{
    const int wave = threadIdx.x >> 6;
    const int lane = threadIdx.x & 63;
    const int s = blockIdx.x * WPB + wave;
    if (s >= S) return;

    int start, end;
    if (seg_start) {
        start = seg_start[s];
        end   = seg_start[s + 1];
    } else {
        int lo0 = 0, hi0 = N, lo1 = 0, hi1 = N;
        while (lo0 < hi0 || lo1 < hi1) {
            if (lo0 < hi0) {
                int mid = (lo0 + hi0) >> 1;
                if (idx[mid] < s) lo0 = mid + 1; else hi0 = mid;
            }
            if (lo1 < hi1) {
                int mid = (lo1 + hi1) >> 1;
                if (idx[mid] < s + 1) lo1 = mid + 1; else hi1 = mid;
            }
        }
        start = lo0; end = lo1;
    }

    // Output element (c, s, d) at c*S*64 + s*64 + d.
    // Lane l covers c = l>>4, d = (l&15)*4 .. +3 (float4-aligned).
    const int c = lane >> 4;
    const long out_f4 = ((long)c * S + s) * 16 + (lane & 15);
    f32x4* __restrict__ out4 = reinterpret_cast<f32x4*>(out);

    if (start >= end) {  // empty segment -> zeros (segment_sum identity)
        f32x4 zz = {0.f, 0.f, 0.f, 0.f};
        __builtin_nontemporal_store(zz, &out4[out_f4]);
        return;
    }

    const float beta = *beta_p;
    const f32x4* __restrict__ x4 = reinterpret_cast<const f32x4*>(x);
    const int last = end - 1;

    float ml[4] = {-1e30f, -1e30f, -1e30f, -1e30f};
    float sm[4] = {0.f, 0.f, 0.f, 0.f};
    float ac[4] = {0.f, 0.f, 0.f, 0.f};

#define PROC(v, vld) {                                              \
        float va[4] = {(v).x, (v).y, (v).z, (v).w};                 \
        _Pragma("unroll")                                           \
        for (int cc = 0; cc < 4; ++cc) {                            \
            float z  = (vld) ? beta * va[cc] : -2e30f;              \
            float mn = fmaxf(ml[cc], z);                            \
            float cr = __expf(ml[cc] - mn);                         \
            float e  = __expf(z - mn);                              \
            sm[cc] = sm[cc] * cr + e;                               \
            ac[cc] = ac[cc] * cr + e * va[cc];                      \
            ml[cc] = mn;                                            \
        }                                                           \
    }

#define LOAD4(d0, d1, d2, d3, base) {                               \
        d0 = x4[(long)(base) * 64 + lane];                          \
        d1 = x4[(long)min((base) + 1, last) * 64 + lane];           \
        d2 = x4[(long)min((base) + 2, last) * 64 + lane];           \
        d3 = x4[(long)min((base) + 3, last) * 64 + lane];           \
    }

    f32x4 a0, a1, a2, a3;
    LOAD4(a0, a1, a2, a3, start);
    int nb = start;
    while (true) {
        const int nxt = nb + 4;
        const bool more = nxt < end;
        f32x4 b0 = a0, b1 = a1, b2 = a2, b3 = a3;
        if (more) LOAD4(b0, b1, b2, b3, nxt);
        PROC(a0, true);
        PROC(a1, nb + 1 < end);
        PROC(a2, nb + 2 < end);
        PROC(a3, nb + 3 < end);
        if (!more) break;
        a0 = b0; a1 = b1; a2 = b2; a3 = b3;
        nb = nxt;
    }
#undef PROC
#undef LOAD4

    f32x4 r = {ac[0] / sm[0], ac[1] / sm[1], ac[2] / sm[2], ac[3] / sm[3]};
    __builtin_nontemporal_store(r, &out4[out_f4]);
}

extern "C" void kernel_launch(void* const* d_in, const int* in_sizes, int n_in,
                              void* d_out, int out_size, void* d_ws, size_t ws_size,
                              hipStream_t stream) {
    const float* x      = (const float*)d_in[0];
    const float* beta_p = (const float*)d_in[1];
    const int*   idx    = (const int*)d_in[2];
    float* out = (float*)d_out;

    const int N = in_sizes[2];          // number of rows / edges
    const int S = out_size / 256;       // out is [4, S, 64]

    int* seg_start = nullptr;
    if (ws_size >= (size_t)(S + 1) * sizeof(int)) {
        seg_start = (int*)d_ws;
        seg_bounds_kernel<<<(N + 255) / 256, 256, 0, stream>>>(idx, seg_start, N, S);
    }

    const int blocks = (S + WPB - 1) / WPB;
    softmax_agg_kernel<<<blocks, 256, 0, stream>>>(x, beta_p, idx, seg_start, out, N, S);
}

// Round 6
// 97.777 us; speedup vs baseline: 1.9603x; 1.1769x over previous
//
#include <hip/hip_runtime.h>
#include <math.h>

// Softmax aggregation (scatter_softmax + weighted segment_sum), single pass.
// x: [N, 4, 64] fp32, idx: [N] int32 SORTED ascending in [0,S),
// out: [4, S, 64] fp32.
//
// Kernel 1 (seg_bounds): start[s] = lower_bound(idx, s) for s in [0, S] -> d_ws.
//
// Kernel 2: one wave per segment; lane l owns elements [4l, 4l+4) of the
// 256-wide row => f32x4 loads, 1KB per wave per row, fully coalesced.
// Online softmax. Structure per segment:
//   (a) pre-issue tail loads (cnt&3 rows, <=3) -- latency hides under (b)
//   (b) clamp-free 4-deep software-pipelined main loop over cnt>>2 batches,
//       nontemporal loads (x is stream-once, 512MB >> L2)
//   (c) masked PROC of the tail registers (pure VALU, data already arrived)
// Masked slots use z=-2e30 => e=0, cr=1 (state unchanged); ml starts at
// -1e30 so the masked path never produces NaN.

#define WPB 4  // waves per block (256 threads)

typedef float f32x4 __attribute__((ext_vector_type(4)));

__global__ __launch_bounds__(256) void seg_bounds_kernel(
    const int* __restrict__ idx, int* __restrict__ start, int N, int S)
{
    int n = blockIdx.x * blockDim.x + threadIdx.x;
    if (n >= N) return;
    int cur = idx[n];
    if (n == 0) {
        for (int s = 0; s <= cur; ++s) start[s] = 0;
    } else {
        int prev = idx[n - 1];
        for (int s = prev + 1; s <= cur; ++s) start[s] = n;
    }
    if (n == N - 1) {
        for (int s = cur + 1; s <= S; ++s) start[s] = N;
    }
}

__global__ __launch_bounds__(256) void softmax_agg_kernel(
    const float* __restrict__ x,
    const float* __restrict__ beta_p,
    const int* __restrict__ idx,
    const int* __restrict__ seg_start,   // null => do binary search
    float* __restrict__ out,
    int N, int S)
{
    const int wave = threadIdx.x >> 6;
    const int lane = threadIdx.x & 63;
    const int s = blockIdx.x * WPB + wave;
    if (s >= S) return;

    int start, end;
    if (seg_start) {
        start = seg_start[s];
        end   = seg_start[s + 1];
    } else {
        int lo0 = 0, hi0 = N, lo1 = 0, hi1 = N;
        while (lo0 < hi0 || lo1 < hi1) {
            if (lo0 < hi0) {
                int mid = (lo0 + hi0) >> 1;
                if (idx[mid] < s) lo0 = mid + 1; else hi0 = mid;
            }
            if (lo1 < hi1) {
                int mid = (lo1 + hi1) >> 1;
                if (idx[mid] < s + 1) lo1 = mid + 1; else hi1 = mid;
            }
        }
        start = lo0; end = lo1;
    }

    // Output element (c, s, d) at c*S*64 + s*64 + d.
    // Lane l covers c = l>>4, d = (l&15)*4 .. +3 (f32x4-aligned).
    const int c = lane >> 4;
    const long out_f4 = ((long)c * S + s) * 16 + (lane & 15);
    f32x4* __restrict__ out4 = reinterpret_cast<f32x4*>(out);

    if (start >= end) {  // empty segment -> zeros (segment_sum identity)
        f32x4 zz = {0.f, 0.f, 0.f, 0.f};
        __builtin_nontemporal_store(zz, &out4[out_f4]);
        return;
    }

    const float beta = *beta_p;
    const f32x4* __restrict__ x4 = reinterpret_cast<const f32x4*>(x);
    const int last    = end - 1;
    const int cnt     = end - start;
    const int nb_main = cnt >> 2;
    const int rem     = cnt & 3;

    // (a) pre-issue tail loads; they complete while the main loop streams.
    f32x4 t0 = {0,0,0,0}, t1 = {0,0,0,0}, t2 = {0,0,0,0};
    if (rem) {
        const int tb = end - rem;
        t0 = x4[(long)tb * 64 + lane];                 // slot 0 valid when rem>0
        t1 = x4[(long)min(tb + 1, last) * 64 + lane];  // dup-clamped if rem<2
        t2 = x4[(long)min(tb + 2, last) * 64 + lane];  // dup-clamped if rem<3
    }

    float ml[4] = {-1e30f, -1e30f, -1e30f, -1e30f};
    float sm[4] = {0.f, 0.f, 0.f, 0.f};
    float ac[4] = {0.f, 0.f, 0.f, 0.f};

#define PROC(v, vld) {                                              \
        float va[4] = {(v).x, (v).y, (v).z, (v).w};                 \
        _Pragma("unroll")                                           \
        for (int cc = 0; cc < 4; ++cc) {                            \
            float z  = (vld) ? beta * va[cc] : -2e30f;              \
            float mn = fmaxf(ml[cc], z);                            \
            float cr = __expf(ml[cc] - mn);                         \
            float e  = __expf(z - mn);                              \
            sm[cc] = sm[cc] * cr + e;                               \
            ac[cc] = ac[cc] * cr + e * va[cc];                      \
            ml[cc] = mn;                                            \
        }                                                           \
    }

#define NTLOAD4(d0, d1, d2, d3, base) {                             \
        d0 = __builtin_nontemporal_load(&x4[(long)(base) * 64 + lane]);     \
        d1 = __builtin_nontemporal_load(&x4[(long)(base) * 64 + 64 + lane]);\
        d2 = __builtin_nontemporal_load(&x4[(long)(base) * 64 + 128 + lane]);\
        d3 = __builtin_nontemporal_load(&x4[(long)(base) * 64 + 192 + lane]);\
    }

    // (b) clamp-free pipelined main loop
    if (nb_main) {
        f32x4 a0, a1, a2, a3;
        NTLOAD4(a0, a1, a2, a3, start);
        int n = start + 4;
        for (int b = 1; b < nb_main; ++b, n += 4) {
            f32x4 b0, b1, b2, b3;
            NTLOAD4(b0, b1, b2, b3, n);
            PROC(a0, true); PROC(a1, true); PROC(a2, true); PROC(a3, true);
            a0 = b0; a1 = b1; a2 = b2; a3 = b3;
        }
        PROC(a0, true); PROC(a1, true); PROC(a2, true); PROC(a3, true);
    }

    // (c) tail: data already resident in t0..t2
    if (rem) {
        PROC(t0, true);
        PROC(t1, rem > 1);
        PROC(t2, rem > 2);
    }
#undef PROC
#undef NTLOAD4

    f32x4 r = {ac[0] / sm[0], ac[1] / sm[1], ac[2] / sm[2], ac[3] / sm[3]};
    __builtin_nontemporal_store(r, &out4[out_f4]);
}

extern "C" void kernel_launch(void* const* d_in, const int* in_sizes, int n_in,
                              void* d_out, int out_size, void* d_ws, size_t ws_size,
                              hipStream_t stream) {
    const float* x      = (const float*)d_in[0];
    const float* beta_p = (const float*)d_in[1];
    const int*   idx    = (const int*)d_in[2];
    float* out = (float*)d_out;

    const int N = in_sizes[2];          // number of rows / edges
    const int S = out_size / 256;       // out is [4, S, 64]

    int* seg_start = nullptr;
    if (ws_size >= (size_t)(S + 1) * sizeof(int)) {
        seg_start = (int*)d_ws;
        seg_bounds_kernel<<<(N + 255) / 256, 256, 0, stream>>>(idx, seg_start, N, S);
    }

    const int blocks = (S + WPB - 1) / WPB;
    softmax_agg_kernel<<<blocks, 256, 0, stream>>>(x, beta_p, idx, seg_start, out, N, S);
}